// Round 7
// baseline (88.743 us; speedup 1.0000x reference)
//
#include <hip/hip_runtime.h>
#include <hip/hip_bf16.h>

#define BSZ  131072
#define DIM  256
#define BM   64
#define NT   512            // 8 waves; wave w owns output cols [w*32, w*32+32)
#define GRID (BSZ / BM)     // 2048

typedef __attribute__((ext_vector_type(8))) short bf16x8;
typedef __attribute__((ext_vector_type(4))) float f32x4;
typedef __attribute__((ext_vector_type(2))) unsigned int u32x2;
typedef __attribute__((ext_vector_type(4))) unsigned short u16x4;

// LDS: ONE full z tile (64 rows x 256 k, bf16). Row = 512B + 16B pad = 528B
// (132 dwords; rows alias mod-32 banks only at distance 8 -> 2-way = free).
#define ZSTRIDE 528
// total 64*528 = 33792 B

__device__ __forceinline__ unsigned short f2bf(float f) {
  unsigned u = __builtin_bit_cast(unsigned, f);
  return (unsigned short)((u + 0x7FFFu + ((u >> 16) & 1u)) >> 16);
}
__device__ __forceinline__ unsigned cvt_pk(float lo, float hi) {
  unsigned r;
  asm("v_cvt_pk_bf16_f32 %0, %1, %2" : "=v"(r) : "v"(lo), "v"(hi));
  return r;
}

// ---------------- prep: f32 W -> bf16 wT, K-major: wT[kb][j][kk] ----------------
__global__ void prep_kernel(const float* __restrict__ Wmu, const float* __restrict__ Wsd,
                            unsigned short* __restrict__ wm, unsigned short* __restrict__ wsd) {
  const int tg = blockIdx.x * 256 + threadIdx.x;   // 16384 threads
  const int j  = tg >> 6, kq = tg & 63;            // row j, k-quad (k0 = kq*4)
  const int dst = ((kq >> 3) << 13) + (j << 5) + ((kq & 7) << 2);
  f32x4 a = *(const f32x4*)(Wmu + j * 256 + kq * 4);
  f32x4 b = *(const f32x4*)(Wsd + j * 256 + kq * 4);
  u16x4 pa, pb;
#pragma unroll
  for (int e = 0; e < 4; ++e) { pa[e] = f2bf(a[e]); pb[e] = f2bf(b[e]); }
  *(u16x4*)(wm + dst)  = pa;
  *(u16x4*)(wsd + dst) = pb;
}

// ---------------- main fused kernel ----------------
__global__ __launch_bounds__(NT, 4)
void main_kernel(const float* __restrict__ z,
                 const unsigned short* __restrict__ wm,
                 const unsigned short* __restrict__ wsd,
                 const float* __restrict__ bmu,
                 const float* __restrict__ bsd,
                 float* __restrict__ out,
                 float* __restrict__ partials) {
  __shared__ unsigned char smem[BM * ZSTRIDE];   // 33792 B
  __shared__ float redbuf[8];
  const int t = threadIdx.x, lane = t & 63, w = t >> 6;
  const int bm = blockIdx.x;

  // ---- stage ENTIRE z tile: 8 x f32x4 per thread, coalesced (8 rows x 128B per instr) ----
  const float* zsrc = z + (size_t)(bm * BM + (t >> 3)) * DIM + (t & 7) * 4;
  const int zw = (t >> 3) * ZSTRIDE + (t & 7) * 8;   // + kb*64

  f32x4 zv[8];
#pragma unroll
  for (int kb = 0; kb < 8; ++kb) zv[kb] = *(const f32x4*)(zsrc + kb * 32);
#pragma unroll
  for (int kb = 0; kb < 8; ++kb) {
    u32x2 p;
    p[0] = cvt_pk(zv[kb][0], zv[kb][1]);
    p[1] = cvt_pk(zv[kb][2], zv[kb][3]);
    *(u32x2*)(smem + zw + kb * 64) = p;
  }
  __syncthreads();   // the ONLY block-wide barrier before the epilogue

  // ---- W fragment sources: direct global, coalesced in K-major wT ----
  // elem = kb*8192 + (w*32 + mi*16 + (lane&15))*32 + (lane>>4)*8
  const int wlo = (lane & 15) * 32 + (lane >> 4) * 8;
  const unsigned short* wmb = wm  + w * 1024 + wlo;   // + mi*512 + kb*8192
  const unsigned short* wsb = wsd + w * 1024 + wlo;

  // z fragment read offset: row nj*16+(lane&15), unit lane>>4
  const int zro = (lane & 15) * ZSTRIDE + (lane >> 4) * 16;   // + nj*16*ZSTRIDE + kb*64

  f32x4 accm[2][4], accl[2][4];   // [mi][nj]
#pragma unroll
  for (int mi = 0; mi < 2; ++mi)
#pragma unroll
    for (int nj = 0; nj < 4; ++nj) { accm[mi][nj] = (f32x4)0.0f; accl[mi][nj] = (f32x4)0.0f; }

  // dist-1 W prefetch
  bf16x8 cwm[2], cws[2];
  cwm[0] = *(const bf16x8*)(wmb);
  cwm[1] = *(const bf16x8*)(wmb + 512);
  cws[0] = *(const bf16x8*)(wsb);
  cws[1] = *(const bf16x8*)(wsb + 512);

  // ---- K loop: 8 steps, NO barriers, compiler free to pipeline ----
#pragma unroll
  for (int kb = 0; kb < 8; ++kb) {
    bf16x8 nwm[2], nws[2];
    if (kb < 7) {
      const int nk = (kb + 1) * 8192;
      nwm[0] = *(const bf16x8*)(wmb + nk);
      nwm[1] = *(const bf16x8*)(wmb + nk + 512);
      nws[0] = *(const bf16x8*)(wsb + nk);
      nws[1] = *(const bf16x8*)(wsb + nk + 512);
    }

    const unsigned char* zb = smem + kb * 64;
    bf16x8 zf[4];
#pragma unroll
    for (int nj = 0; nj < 4; ++nj)
      zf[nj] = *(const bf16x8*)(zb + nj * 16 * ZSTRIDE + zro);

#pragma unroll
    for (int mi = 0; mi < 2; ++mi)
#pragma unroll
      for (int nj = 0; nj < 4; ++nj) {
        accm[mi][nj] = __builtin_amdgcn_mfma_f32_16x16x32_bf16(cwm[mi], zf[nj], accm[mi][nj], 0, 0, 0);
        accl[mi][nj] = __builtin_amdgcn_mfma_f32_16x16x32_bf16(cws[mi], zf[nj], accl[mi][nj], 0, 0, 0);
      }

    if (kb < 7) {
      cwm[0] = nwm[0]; cwm[1] = nwm[1];
      cws[0] = nws[0]; cws[1] = nws[1];
    }
  }

  // ---- epilogue: bias + relu + KL + vectorized f32x4 stores ----
  float klp = 0.0f;
#pragma unroll
  for (int mi = 0; mi < 2; ++mi) {
    const int colb = w * 32 + mi * 16 + ((lane >> 4) << 2);
    const f32x4 b4m = *(const f32x4*)(bmu + colb);
    const f32x4 b4s = *(const f32x4*)(bsd + colb);
#pragma unroll
    for (int nj = 0; nj < 4; ++nj) {
      const size_t row = (size_t)(bm * BM + nj * 16 + (lane & 15));
      f32x4 mu4;
#pragma unroll
      for (int r = 0; r < 4; ++r) {
        float mu = fmaxf(accm[mi][nj][r] + b4m[r], 0.0f);
        float ls = fmaxf(accl[mi][nj][r] + b4s[r], 0.0f);
        float iv = __expf(-2.0f * ls);
        klp += fmaf(mu * mu, iv, iv) + 2.0f * ls;   // (1+mu^2)*iv + 2*ls; -1 folded below
        mu4[r] = mu;
      }
      *(f32x4*)(out + row * DIM + colb) = mu4;
    }
  }
  klp = 0.5f * (klp - 32.0f);   // 32 elements per lane

#pragma unroll
  for (int off = 32; off; off >>= 1) klp += __shfl_down(klp, off);
  if (lane == 0) redbuf[w] = klp;
  __syncthreads();
  if (t == 0) {
    float s = 0.0f;
#pragma unroll
    for (int i = 0; i < 8; ++i) s += redbuf[i];
    partials[bm] = s;
  }
}

// ---------------- finalize ----------------
__global__ void fin_kernel(const float* __restrict__ partials, float* __restrict__ out) {
  __shared__ double red[256];
  double s = 0.0;
  for (int i = threadIdx.x; i < GRID; i += 256) s += (double)partials[i];
  red[threadIdx.x] = s;
  __syncthreads();
  for (int st = 128; st > 0; st >>= 1) {
    if ((int)threadIdx.x < st) red[threadIdx.x] += red[threadIdx.x + st];
    __syncthreads();
  }
  if (threadIdx.x == 0) out[(size_t)BSZ * DIM] = (float)(red[0] / (double)BSZ);
}

// ---------------- launch ----------------
// ws: [0,8192) float partials[2048]; [8192,+128K) wT_mu; [139264,+128K) wT_sd. Total 270336 B.
extern "C" void kernel_launch(void* const* d_in, const int* in_sizes, int n_in,
                              void* d_out, int out_size, void* d_ws, size_t ws_size,
                              hipStream_t stream) {
  const float* z   = (const float*)d_in[0];
  const float* Wmu = (const float*)d_in[1];
  const float* bmu = (const float*)d_in[2];
  const float* Wsd = (const float*)d_in[3];
  const float* bsd = (const float*)d_in[4];
  float* out = (float*)d_out;

  float* partials     = (float*)d_ws;
  unsigned short* wm  = (unsigned short*)((char*)d_ws + 8192);
  unsigned short* wsd = wm + DIM * DIM;

  prep_kernel<<<64, 256, 0, stream>>>(Wmu, Wsd, wm, wsd);
  main_kernel<<<GRID, NT, 0, stream>>>(z, wm, wsd, bmu, bsd, out, partials);
  fin_kernel<<<1, 256, 0, stream>>>(partials, out);
}